// Round 2
// baseline (751.837 us; speedup 1.0000x reference)
//
#include <hip/hip_runtime.h>
#include <cstdint>
#include <cstddef>

using f32x4  = __attribute__((ext_vector_type(4))) float;
using bf16x8 = __attribute__((ext_vector_type(8))) short;

__device__ __forceinline__ float bflo(unsigned int u){ return __uint_as_float(u << 16); }
__device__ __forceinline__ unsigned short f2bf(float f){
  unsigned int u = __float_as_uint(f);
  return (unsigned short)((u + 0x7fffu + ((u >> 16) & 1u)) >> 16);
}

// swizzle for 512B rows (256 bf16): toggle 16B-slot bits with row&7
#define SWZ(o) ((o) ^ ((((o) >> 9) & 7) << 4))

// ---------------------------------------------------------------------------
__global__ void k_wt(const float* __restrict__ Wk, const float* __restrict__ Wv,
                     unsigned short* __restrict__ Wt){
  int idx = blockIdx.x * 256 + threadIdx.x;   // 32768 total
  int n = idx >> 8, kk = idx & 255;
  float w = (n < 64) ? Wk[kk * 64 + n] : Wv[kk * 64 + (n - 64)];
  Wt[idx] = f2bf(w);
}

__global__ void k_init(const float* __restrict__ noise, const float* __restrict__ mu,
                       const float* __restrict__ lsig, float* __restrict__ slots){
  int idx = blockIdx.x * 256 + threadIdx.x;   // 81920 total
  int d = idx & 63;
  slots[idx] = mu[d] + __expf(lsig[d]) * noise[idx];
}

// ---------------------------------------------------------------------------
// Fused LN + (x@Wk | x@Wv) -> kb bf16 [B*N][64], vb bf16 [B*N][64]
__global__ __launch_bounds__(256) void k_lnkv(
    const float* __restrict__ x, const float* __restrict__ lng, const float* __restrict__ lnb,
    const unsigned short* __restrict__ Wt,
    unsigned short* __restrict__ kb, unsigned short* __restrict__ vb){
  extern __shared__ char smem[];
  char* As = smem;            // 64 x 256 bf16, swizzled (32KB)
  char* Bs = smem + 32768;    // 64 x 256 bf16, swizzled (32KB); Cs aliases this
  char* Cs = smem + 32768;    // 64 x 64 bf16 output staging (8KB, aliased)
  const int t = threadIdx.x;
  const int lane = t & 63, w = t >> 6;
  const int gm0 = blockIdx.x * 64;

  const float4 g4 = *(const float4*)(lng + lane * 4);
  const float4 b4 = *(const float4*)(lnb + lane * 4);

  #pragma unroll
  for (int bb = 0; bb < 2; ++bb){
    float4 xv[8];
    #pragma unroll
    for (int j = 0; j < 8; ++j){
      int r = w * 16 + bb * 8 + j;
      xv[j] = *(const float4*)(x + (size_t)(gm0 + r) * 256 + lane * 4);
    }
    #pragma unroll
    for (int j = 0; j < 8; ++j){
      int r = w * 16 + bb * 8 + j;
      float4 v = xv[j];
      float s  = v.x + v.y + v.z + v.w;
      float s2 = v.x * v.x + v.y * v.y + v.z * v.z + v.w * v.w;
      #pragma unroll
      for (int off = 32; off >= 1; off >>= 1){
        s  += __shfl_xor(s,  off);
        s2 += __shfl_xor(s2, off);
      }
      float mean = s * (1.f / 256.f);
      float var  = s2 * (1.f / 256.f) - mean * mean;
      float rstd = rsqrtf(var + 1e-5f);
      unsigned int p0 = (unsigned)f2bf((v.x - mean) * rstd * g4.x + b4.x) |
                        ((unsigned)f2bf((v.y - mean) * rstd * g4.y + b4.y) << 16);
      unsigned int p1 = (unsigned)f2bf((v.z - mean) * rstd * g4.z + b4.z) |
                        ((unsigned)f2bf((v.w - mean) * rstd * g4.w + b4.w) << 16);
      int off8 = r * 512 + lane * 8;
      *(uint2*)(As + SWZ(off8)) = make_uint2(p0, p1);
    }
  }

  const int wm = w >> 1, wn = w & 1;
  const int l15 = lane & 15, l4 = lane >> 4;

  #pragma unroll 1
  for (int pass = 0; pass < 2; ++pass){
    // stage Bs for this pass (pass0: Wt rows 0..63 = Wk^T; pass1: rows 64..127)
    __syncthreads();   // prior-pass Cs reads (and pass0: nothing) complete
    {
      const char* wp = (const char*)(Wt + (size_t)pass * 64 * 256);
      #pragma unroll
      for (int j = 0; j < 8; ++j){
        int c = t + 256 * j;
        *(uint4*)(Bs + SWZ(c * 16)) = *(const uint4*)(wp + c * 16);
      }
    }
    __syncthreads();

    f32x4 acc[2][2];
    #pragma unroll
    for (int i = 0; i < 2; ++i)
      #pragma unroll
      for (int j = 0; j < 2; ++j)
        acc[i][j] = (f32x4){0.f, 0.f, 0.f, 0.f};

    #pragma unroll
    for (int kk = 0; kk < 8; ++kk){
      bf16x8 a[2], bfr[2];
      #pragma unroll
      for (int i = 0; i < 2; ++i){
        int ar = wm * 32 + i * 16 + l15;
        a[i]   = *(const bf16x8*)(As + SWZ(ar * 512 + kk * 64 + l4 * 16));
        int br = wn * 32 + i * 16 + l15;
        bfr[i] = *(const bf16x8*)(Bs + SWZ(br * 512 + kk * 64 + l4 * 16));
      }
      #pragma unroll
      for (int i = 0; i < 2; ++i)
        #pragma unroll
        for (int j = 0; j < 2; ++j)
          acc[i][j] = __builtin_amdgcn_mfma_f32_16x16x32_bf16(a[i], bfr[j], acc[i][j], 0, 0, 0);
    }
    __syncthreads();   // all waves done reading Bs before Cs (alias) write

    // stage C tile in LDS (rows 128B, swizzle by row&7 on 16B slots)
    #pragma unroll
    for (int i = 0; i < 2; ++i)
      #pragma unroll
      for (int j = 0; j < 2; ++j)
        #pragma unroll
        for (int reg = 0; reg < 4; ++reg){
          int row = wm * 32 + i * 16 + l4 * 4 + reg;
          int colb = (wn * 32 + j * 16 + l15) * 2;
          *(unsigned short*)(Cs + row * 128 + (colb ^ ((row & 7) << 4))) = f2bf(acc[i][j][reg]);
        }
    __syncthreads();

    unsigned short* dst = pass ? vb : kb;
    #pragma unroll
    for (int q2 = 0; q2 < 2; ++q2){
      int idx = t + 256 * q2, r = idx >> 3, c = idx & 7;
      uint4 val = *(const uint4*)(Cs + r * 128 + ((c * 16) ^ ((r & 7) << 4)));
      *(uint4*)((char*)dst + ((size_t)(gm0 + r)) * 128 + c * 16) = val;
    }
  }
}

// ---------------------------------------------------------------------------
// transpose vb [B*N][64] -> vT [B][64][4096] (bf16), 64x64 tiles
__global__ __launch_bounds__(256) void k_vt(const unsigned short* __restrict__ vb,
                                            unsigned short* __restrict__ vT){
  __shared__ unsigned short T[64][72];
  const int t = threadIdx.x, b = blockIdx.y, n0 = blockIdx.x * 64;
  #pragma unroll
  for (int q = 0; q < 2; ++q){
    int idx = t + 256 * q, n = idx >> 3, c = idx & 7;
    uint4 val = *(const uint4*)(vb + ((size_t)(b * 4096 + n0 + n)) * 64 + c * 8);
    const unsigned short* e = (const unsigned short*)&val;
    #pragma unroll
    for (int j = 0; j < 8; ++j){
      int row = c * 8 + j;
      T[row][n ^ (((row >> 3) & 7) << 3)] = e[j];
    }
  }
  __syncthreads();
  #pragma unroll
  for (int q = 0; q < 2; ++q){
    int idx = t + 256 * q, dd = idx >> 3, c = idx & 7;
    int cc = c ^ ((dd >> 3) & 7);
    uint4 val = *(const uint4*)(&T[dd][cc * 8]);
    *(uint4*)(vT + ((size_t)(b * 64 + dd)) * 4096 + n0 + c * 8) = val;
  }
}

// ---------------------------------------------------------------------------
__global__ __launch_bounds__(64) void k_slotq(
    const float* __restrict__ slots, const float* __restrict__ lng, const float* __restrict__ lnb,
    const float* __restrict__ Wq, float* __restrict__ qws){
  int bk = blockIdx.x, d = threadIdx.x;
  float s = slots[bk * 64 + d];
  float s1 = s, s2 = s * s;
  #pragma unroll
  for (int off = 32; off >= 1; off >>= 1){
    s1 += __shfl_xor(s1, off);
    s2 += __shfl_xor(s2, off);
  }
  float m = s1 * (1.f / 64.f);
  float var = s2 * (1.f / 64.f) - m * m;
  float rstd = rsqrtf(var + 1e-5f);
  float xn = (s - m) * rstd * lng[d] + lnb[d];
  __shared__ __align__(16) float xsh[64];
  xsh[d] = xn;
  __syncthreads();
  float q = 0.f;
  #pragma unroll
  for (int i = 0; i < 64; ++i) q += xsh[i] * Wq[i * 64 + d];
  qws[bk * 64 + d] = q;
}

// ---------------------------------------------------------------------------
// MFMA attention: per (b, 128-n chunk): QK^T -> softmax over ks -> P (bf16 LDS)
// -> S atomics, attn write (last iter), U += P @ v via vT
__global__ __launch_bounds__(256) void k_attn2(
    const unsigned short* __restrict__ kb, const unsigned short* __restrict__ vT,
    const float* __restrict__ qws, float* __restrict__ Sws, float* __restrict__ Uws,
    float* __restrict__ attn_out, int write_attn){
  __shared__ __align__(16) char sm[45056];
  char* kT  = sm;            // [128][64] bf16 swz (16KB)
  char* vTs = sm + 16384;    // [64][128] bf16 swz (16KB)
  char* qs  = sm + 32768;    // [32][64] bf16 swz (4KB)
  char* Ps  = sm + 36864;    // [32][128] bf16 swz (8KB)
  const int t = threadIdx.x, lane = t & 63, w = t >> 6;
  const int l15 = lane & 15, g = lane >> 4;
  const int b = blockIdx.y, n0 = blockIdx.x * 128;

  // stage q (20 rows x 64 f32 -> bf16)
  if (t < 160){
    int r = t >> 3, c = t & 7;
    const float4* qp = (const float4*)(qws + (size_t)b * 1280 + r * 64 + c * 8);
    float4 a0 = qp[0], a1 = qp[1];
    uint4 pk;
    pk.x = (unsigned)f2bf(a0.x) | ((unsigned)f2bf(a0.y) << 16);
    pk.y = (unsigned)f2bf(a0.z) | ((unsigned)f2bf(a0.w) << 16);
    pk.z = (unsigned)f2bf(a1.x) | ((unsigned)f2bf(a1.y) << 16);
    pk.w = (unsigned)f2bf(a1.z) | ((unsigned)f2bf(a1.w) << 16);
    *(uint4*)(qs + r * 128 + ((c * 16) ^ ((r & 7) << 4))) = pk;
  }
  // stage k tile [128][64]
  {
    const char* kbp = (const char*)kb + (size_t)b * 4096 * 128;
    #pragma unroll
    for (int j = 0; j < 4; ++j){
      int idx = t + 256 * j, r = idx >> 3, c = idx & 7;
      uint4 val = *(const uint4*)(kbp + ((size_t)(n0 + r)) * 128 + c * 16);
      *(uint4*)(kT + r * 128 + ((c * 16) ^ ((r & 7) << 4))) = val;
    }
  }
  // stage vT tile [64][128]
  {
    const char* vtp = (const char*)vT + (size_t)b * 64 * 8192;
    #pragma unroll
    for (int j = 0; j < 4; ++j){
      int idx = t + 256 * j, r = idx >> 4, c = idx & 15;
      uint4 val = *(const uint4*)(vtp + (size_t)r * 8192 + n0 * 2 + c * 16);
      *(uint4*)(vTs + r * 256 + ((c * 16) ^ ((r & 7) << 4))) = val;
    }
  }
  __syncthreads();

  // QK^T: wave w handles n-window w*32..w*32+31; C[ks][n]
  f32x4 c2[2][2];
  #pragma unroll
  for (int kt = 0; kt < 2; ++kt)
    #pragma unroll
    for (int nt = 0; nt < 2; ++nt)
      c2[kt][nt] = (f32x4){0.f, 0.f, 0.f, 0.f};
  #pragma unroll
  for (int kst = 0; kst < 2; ++kst){
    bf16x8 aq[2], bk2[2];
    #pragma unroll
    for (int kt = 0; kt < 2; ++kt){
      int row = kt * 16 + l15;
      aq[kt] = *(const bf16x8*)(qs + row * 128 + ((kst * 64 + g * 16) ^ ((row & 7) << 4)));
    }
    #pragma unroll
    for (int nt = 0; nt < 2; ++nt){
      int row = w * 32 + nt * 16 + l15;
      bk2[nt] = *(const bf16x8*)(kT + row * 128 + ((kst * 64 + g * 16) ^ ((row & 7) << 4)));
    }
    #pragma unroll
    for (int kt = 0; kt < 2; ++kt)
      #pragma unroll
      for (int nt = 0; nt < 2; ++nt)
        c2[kt][nt] = __builtin_amdgcn_mfma_f32_16x16x32_bf16(aq[kt], bk2[nt], c2[kt][nt], 0, 0, 0);
  }

  // scale + mask (ks = kt*16 + g*4 + reg; kt==1 && g>0 -> ks>=20 invalid)
  float p[2][2][4];
  #pragma unroll
  for (int kt = 0; kt < 2; ++kt)
    #pragma unroll
    for (int nt = 0; nt < 2; ++nt)
      #pragma unroll
      for (int reg = 0; reg < 4; ++reg)
        p[kt][nt][reg] = c2[kt][nt][reg] * 0.125f;
  if (g){
    #pragma unroll
    for (int nt = 0; nt < 2; ++nt)
      #pragma unroll
      for (int reg = 0; reg < 4; ++reg)
        p[1][nt][reg] = -1e30f;
  }

  // softmax over ks per n-column
  #pragma unroll
  for (int nt = 0; nt < 2; ++nt){
    float mx = p[0][nt][0];
    #pragma unroll
    for (int reg = 1; reg < 4; ++reg) mx = fmaxf(mx, p[0][nt][reg]);
    #pragma unroll
    for (int reg = 0; reg < 4; ++reg) mx = fmaxf(mx, p[1][nt][reg]);
    mx = fmaxf(mx, __shfl_xor(mx, 16));
    mx = fmaxf(mx, __shfl_xor(mx, 32));
    float s = 0.f;
    #pragma unroll
    for (int kt = 0; kt < 2; ++kt)
      #pragma unroll
      for (int reg = 0; reg < 4; ++reg){
        float e = __expf(p[kt][nt][reg] - mx);
        p[kt][nt][reg] = e; s += e;
      }
    s += __shfl_xor(s, 16);
    s += __shfl_xor(s, 32);
    float inv = 1.f / s;
    #pragma unroll
    for (int kt = 0; kt < 2; ++kt)
      #pragma unroll
      for (int reg = 0; reg < 4; ++reg)
        p[kt][nt][reg] *= inv;
  }

  // S[ks] += sum_n attn
  {
    float sr[2][4];
    #pragma unroll
    for (int kt = 0; kt < 2; ++kt)
      #pragma unroll
      for (int reg = 0; reg < 4; ++reg)
        sr[kt][reg] = p[kt][0][reg] + p[kt][1][reg];
    #pragma unroll
    for (int off = 1; off <= 8; off <<= 1)
      #pragma unroll
      for (int kt = 0; kt < 2; ++kt)
        #pragma unroll
        for (int reg = 0; reg < 4; ++reg)
          sr[kt][reg] += __shfl_xor(sr[kt][reg], off);
    if (l15 == 0){
      #pragma unroll
      for (int kt = 0; kt < 2; ++kt)
        #pragma unroll
        for (int reg = 0; reg < 4; ++reg){
          int ks = kt * 16 + g * 4 + reg;
          if (ks < 20) atomicAdd(Sws + b * 20 + ks, sr[kt][reg]);
        }
    }
  }

  if (write_attn){
    #pragma unroll
    for (int kt = 0; kt < 2; ++kt)
      #pragma unroll
      for (int nt = 0; nt < 2; ++nt)
        #pragma unroll
        for (int reg = 0; reg < 4; ++reg){
          int ks = kt * 16 + g * 4 + reg;
          if (ks < 20)
            attn_out[((size_t)(b * 20 + ks)) * 4096 + n0 + w * 32 + nt * 16 + l15] = p[kt][nt][reg];
        }
  }

  // P -> LDS bf16 (all 32 rows written; rows >=20 are zeros)
  #pragma unroll
  for (int kt = 0; kt < 2; ++kt)
    #pragma unroll
    for (int nt = 0; nt < 2; ++nt)
      #pragma unroll
      for (int reg = 0; reg < 4; ++reg){
        int row = kt * 16 + g * 4 + reg;
        int colb = (w * 32 + nt * 16 + l15) * 2;
        *(unsigned short*)(Ps + row * 256 + (colb ^ ((row & 7) << 4))) = f2bf(p[kt][nt][reg]);
      }
  __syncthreads();

  // PV: wave w computes U[ks][d] for d in w*16..w*16+15, over all 128 n
  f32x4 u[2];
  u[0] = (f32x4){0.f,0.f,0.f,0.f};
  u[1] = (f32x4){0.f,0.f,0.f,0.f};
  #pragma unroll
  for (int kst = 0; kst < 4; ++kst){
    bf16x8 pa[2], bv;
    #pragma unroll
    for (int kt = 0; kt < 2; ++kt){
      int row = kt * 16 + l15;
      pa[kt] = *(const bf16x8*)(Ps + row * 256 + ((kst * 64 + g * 16) ^ ((row & 7) << 4)));
    }
    {
      int row = w * 16 + l15;
      bv = *(const bf16x8*)(vTs + row * 256 + ((kst * 64 + g * 16) ^ ((row & 7) << 4)));
    }
    #pragma unroll
    for (int kt = 0; kt < 2; ++kt)
      u[kt] = __builtin_amdgcn_mfma_f32_16x16x32_bf16(pa[kt], bv, u[kt], 0, 0, 0);
  }
  #pragma unroll
  for (int kt = 0; kt < 2; ++kt)
    #pragma unroll
    for (int reg = 0; reg < 4; ++reg){
      int ks = kt * 16 + g * 4 + reg;
      if (ks < 20)
        atomicAdd(Uws + ((size_t)(b * 20 + ks)) * 64 + w * 16 + l15, u[kt][reg]);
    }
}

// ---------------------------------------------------------------------------
// updates=U/(S+eps) -> GRU -> LN -> MLP -> slots ; 4 (b,k) pairs per block
__global__ __launch_bounds__(256) void k_gru(
    float* __restrict__ slots, const float* __restrict__ Uws, const float* __restrict__ Sws,
    const float* __restrict__ Wih, const float* __restrict__ Whh,
    const float* __restrict__ bih, const float* __restrict__ bhh,
    const float* __restrict__ lmg, const float* __restrict__ lmb,
    const float* __restrict__ W1, const float* __restrict__ b1,
    const float* __restrict__ W2, const float* __restrict__ b2,
    float* __restrict__ out_slots, int last){
  const int t = threadIdx.x, d = t & 63, w = t >> 6;
  const int bk = blockIdx.x * 4 + w;
  float rs = 1.f / (Sws[bk] + 1e-8f);
  float u = Uws[bk * 64 + d] * rs;
  float prev = slots[bk * 64 + d];
  __shared__ __align__(16) float ush[4][64], psh[4][64], hsh[4][64], hidsh[4][256];
  ush[w][d] = u; psh[w][d] = prev;
  __syncthreads();
  float g_i[3], g_h[3];
  #pragma unroll
  for (int g = 0; g < 3; ++g){
    const float4* wi = (const float4*)(Wih + (size_t)(g * 64 + d) * 64);
    const float4* wh = (const float4*)(Whh + (size_t)(g * 64 + d) * 64);
    const float4* u4 = (const float4*)ush[w];
    const float4* p4 = (const float4*)psh[w];
    float ai = bih[g * 64 + d], ah = bhh[g * 64 + d];
    #pragma unroll
    for (int c = 0; c < 16; ++c){
      float4 wiv = wi[c], whv = wh[c], uv = u4[c], pv = p4[c];
      ai += wiv.x*uv.x + wiv.y*uv.y + wiv.z*uv.z + wiv.w*uv.w;
      ah += whv.x*pv.x + whv.y*pv.y + whv.z*pv.z + whv.w*pv.w;
    }
    g_i[g] = ai; g_h[g] = ah;
  }
  float r = 1.f / (1.f + __expf(-(g_i[0] + g_h[0])));
  float z = 1.f / (1.f + __expf(-(g_i[1] + g_h[1])));
  float nv = tanhf(g_i[2] + r * g_h[2]);
  float snew = (1.f - z) * nv + z * prev;
  float s1 = snew, s2 = snew * snew;
  #pragma unroll
  for (int off = 32; off >= 1; off >>= 1){
    s1 += __shfl_xor(s1, off);
    s2 += __shfl_xor(s2, off);
  }
  float m = s1 * (1.f / 64.f);
  float var = s2 * (1.f / 64.f) - m * m;
  float rstd = rsqrtf(var + 1e-5f);
  float h = (snew - m) * rstd * lmg[d] + lmb[d];
  hsh[w][d] = h;
  __syncthreads();
  float hid[4];
  #pragma unroll
  for (int jj = 0; jj < 4; ++jj){
    int j = jj * 64 + d;
    float a = b1[j];
    #pragma unroll
    for (int i = 0; i < 64; ++i) a += hsh[w][i] * W1[i * 256 + j];
    hid[jj] = fmaxf(a, 0.f);
  }
  #pragma unroll
  for (int jj = 0; jj < 4; ++jj) hidsh[w][jj * 64 + d] = hid[jj];
  __syncthreads();
  float o = b2[d];
  #pragma unroll 8
  for (int j = 0; j < 256; ++j) o += hidsh[w][j] * W2[j * 64 + d];
  float sf = snew + o;
  slots[bk * 64 + d] = sf;
  if (last) out_slots[bk * 64 + d] = sf;
}

// ---------------------------------------------------------------------------
extern "C" void kernel_launch(void* const* d_in, const int* in_sizes, int n_in,
                              void* d_out, int out_size, void* d_ws, size_t ws_size,
                              hipStream_t stream){
  const float* inputs = (const float*)d_in[0];
  const float* noise  = (const float*)d_in[1];
  const float* mu     = (const float*)d_in[2];
  const float* lsig   = (const float*)d_in[3];
  const float* ln_in_g= (const float*)d_in[4];
  const float* ln_in_b= (const float*)d_in[5];
  const float* Wk     = (const float*)d_in[6];
  const float* Wv     = (const float*)d_in[7];
  const float* Wq     = (const float*)d_in[8];
  const float* ln_s_g = (const float*)d_in[9];
  const float* ln_s_b = (const float*)d_in[10];
  const float* Wih    = (const float*)d_in[11];
  const float* Whh    = (const float*)d_in[12];
  const float* bih    = (const float*)d_in[13];
  const float* bhh    = (const float*)d_in[14];
  const float* lmg    = (const float*)d_in[15];
  const float* lmb    = (const float*)d_in[16];
  const float* W1     = (const float*)d_in[17];
  const float* b1     = (const float*)d_in[18];
  const float* W2     = (const float*)d_in[19];
  const float* b2     = (const float*)d_in[20];

  char* ws = (char*)d_ws;
  unsigned short* kb  = (unsigned short*)ws;                  // 33,554,432 B
  unsigned short* vb  = (unsigned short*)(ws + 33554432);     // 33,554,432 B
  unsigned short* vT  = (unsigned short*)(ws + 67108864);     // 33,554,432 B
  unsigned short* Wt  = (unsigned short*)(ws + 100663296);    // 65,536 B
  float* slots        = (float*)(ws + 100728832);             // 327,680 B
  float* qws          = (float*)(ws + 101056512);             // 327,680 B
  float* Uws          = (float*)(ws + 101384192);             // 327,680 B
  float* Sws          = (float*)(ws + 101711872);             // 5,120 B

  float* slots_out = (float*)d_out;
  float* attn_out  = slots_out + 81920;

  hipLaunchKernelGGL(k_wt,   dim3(128),  dim3(256), 0, stream, Wk, Wv, Wt);
  hipLaunchKernelGGL(k_init, dim3(320),  dim3(256), 0, stream, noise, mu, lsig, slots);
  hipLaunchKernelGGL(k_lnkv, dim3(4096), dim3(256), 65536, stream, inputs, ln_in_g, ln_in_b, Wt, kb, vb);
  hipLaunchKernelGGL(k_vt,   dim3(64, 64), dim3(256), 0, stream, vb, vT);

  for (int it = 0; it < 3; ++it){
    hipMemsetAsync(Uws, 0, (81920 + 1280) * sizeof(float), stream);
    hipLaunchKernelGGL(k_slotq, dim3(1280), dim3(64), 0, stream, slots, ln_s_g, ln_s_b, Wq, qws);
    hipLaunchKernelGGL(k_attn2, dim3(32, 64), dim3(256), 0, stream, kb, vT, qws, Sws, Uws,
                       attn_out, (it == 2) ? 1 : 0);
    hipLaunchKernelGGL(k_gru, dim3(320), dim3(256), 0, stream, slots, Uws, Sws,
                       Wih, Whh, bih, bhh, lmg, lmb, W1, b1, W2, b2,
                       slots_out, (it == 2) ? 1 : 0);
  }
}

// Round 3
// 418.912 us; speedup vs baseline: 1.7947x; 1.7947x over previous
//
#include <hip/hip_runtime.h>
#include <cstdint>
#include <cstddef>

using f32x4  = __attribute__((ext_vector_type(4))) float;
using bf16x8 = __attribute__((ext_vector_type(8))) short;

__device__ __forceinline__ float bflo(unsigned int u){ return __uint_as_float(u << 16); }
__device__ __forceinline__ unsigned short f2bf(float f){
  unsigned int u = __float_as_uint(f);
  return (unsigned short)((u + 0x7fffu + ((u >> 16) & 1u)) >> 16);
}

// swizzles: XOR 16B-slot bits with row&7 (row = 512B or 128B)
#define SWZ(o)    ((o) ^ ((((o) >> 9) & 7) << 4))
#define SWZ128(o) ((o) ^ ((((o) >> 7) & 7) << 4))

// ---------------------------------------------------------------------------
__global__ void k_wt(const float* __restrict__ Wk, const float* __restrict__ Wv,
                     unsigned short* __restrict__ Wt){
  int idx = blockIdx.x * 256 + threadIdx.x;   // 32768 total
  int n = idx >> 8, kk = idx & 255;
  float w = (n < 64) ? Wk[kk * 64 + n] : Wv[kk * 64 + (n - 64)];
  Wt[idx] = f2bf(w);
}

__global__ void k_init(const float* __restrict__ noise, const float* __restrict__ mu,
                       const float* __restrict__ lsig, float* __restrict__ slots){
  int idx = blockIdx.x * 256 + threadIdx.x;   // 81920 total
  int d = idx & 63;
  slots[idx] = mu[d] + __expf(lsig[d]) * noise[idx];
}

// ---------------------------------------------------------------------------
// Pack slot-path weights into MFMA A-fragment order (bf16).
// Frag f of matrix [O][K]: lane l, elem e -> SRC[row = jt*16+(l&15)][col = kst*32+(l>>4)*8+e]
// where jt = f / (K/32), kst = f % (K/32). Packed elem index = (f*64+l)*8+e.
__global__ void k_wprep(const float* __restrict__ Wih, const float* __restrict__ Whh,
                        const float* __restrict__ W1,  const float* __restrict__ W2,
                        const float* __restrict__ Wq,
                        unsigned short* __restrict__ PWih, unsigned short* __restrict__ PWhh,
                        unsigned short* __restrict__ PW1T, unsigned short* __restrict__ PW2T,
                        unsigned short* __restrict__ PWq){
  int idx = blockIdx.x * 256 + threadIdx.x;   // 61440 total
  int rel, kstN;
  const float* src; unsigned short* dst; int mode;
  if (idx < 12288)      { rel = idx;          kstN = 2; src = Wih; dst = PWih; mode = 0; }
  else if (idx < 24576) { rel = idx - 12288;  kstN = 2; src = Whh; dst = PWhh; mode = 0; }
  else if (idx < 40960) { rel = idx - 24576;  kstN = 2; src = W1;  dst = PW1T; mode = 1; }
  else if (idx < 57344) { rel = idx - 40960;  kstN = 8; src = W2;  dst = PW2T; mode = 2; }
  else                  { rel = idx - 57344;  kstN = 2; src = Wq;  dst = PWq;  mode = 3; }
  int e = rel & 7, lane = (rel >> 3) & 63, f = rel >> 9;
  int jt = f / kstN, kst = f - jt * kstN;
  int row = jt * 16 + (lane & 15);
  int col = kst * 32 + (lane >> 4) * 8 + e;
  float v;
  if (mode == 0)      v = src[row * 64 + col];    // Wih/Whh [192][64]: A[j][d]=Wih[j][d]
  else if (mode == 1) v = src[col * 256 + row];   // W1 [64][256]: A[j][d]=W1[d][j]
  else if (mode == 2) v = src[col * 64 + row];    // W2 [256][64]: A[d][j]=W2[j][d]
  else                v = src[col * 64 + row];    // Wq [64][64]:  A[j][d]=Wq[d][j]
  dst[rel] = f2bf(v);
}

// ---------------------------------------------------------------------------
// Fused LN + (x@Wk | x@Wv) -> kb bf16 [B*N][64], vb bf16 [B*N][64]
__global__ __launch_bounds__(256) void k_lnkv(
    const float* __restrict__ x, const float* __restrict__ lng, const float* __restrict__ lnb,
    const unsigned short* __restrict__ Wt,
    unsigned short* __restrict__ kb, unsigned short* __restrict__ vb){
  extern __shared__ char smem[];
  char* As = smem;            // 64 x 256 bf16, swizzled (32KB)
  char* Bs = smem + 32768;    // 64 x 256 bf16, swizzled (32KB); Cs aliases this
  char* Cs = smem + 32768;    // 64 x 64 bf16 output staging (8KB, aliased)
  const int t = threadIdx.x;
  const int lane = t & 63, w = t >> 6;
  const int gm0 = blockIdx.x * 64;

  const float4 g4 = *(const float4*)(lng + lane * 4);
  const float4 b4 = *(const float4*)(lnb + lane * 4);

  #pragma unroll
  for (int bb = 0; bb < 2; ++bb){
    float4 xv[8];
    #pragma unroll
    for (int j = 0; j < 8; ++j){
      int r = w * 16 + bb * 8 + j;
      xv[j] = *(const float4*)(x + (size_t)(gm0 + r) * 256 + lane * 4);
    }
    #pragma unroll
    for (int j = 0; j < 8; ++j){
      int r = w * 16 + bb * 8 + j;
      float4 v = xv[j];
      float s  = v.x + v.y + v.z + v.w;
      float s2 = v.x * v.x + v.y * v.y + v.z * v.z + v.w * v.w;
      #pragma unroll
      for (int off = 32; off >= 1; off >>= 1){
        s  += __shfl_xor(s,  off);
        s2 += __shfl_xor(s2, off);
      }
      float mean = s * (1.f / 256.f);
      float var  = s2 * (1.f / 256.f) - mean * mean;
      float rstd = rsqrtf(var + 1e-5f);
      unsigned int p0 = (unsigned)f2bf((v.x - mean) * rstd * g4.x + b4.x) |
                        ((unsigned)f2bf((v.y - mean) * rstd * g4.y + b4.y) << 16);
      unsigned int p1 = (unsigned)f2bf((v.z - mean) * rstd * g4.z + b4.z) |
                        ((unsigned)f2bf((v.w - mean) * rstd * g4.w + b4.w) << 16);
      int off8 = r * 512 + lane * 8;
      *(uint2*)(As + SWZ(off8)) = make_uint2(p0, p1);
    }
  }

  const int wm = w >> 1, wn = w & 1;
  const int l15 = lane & 15, l4 = lane >> 4;

  #pragma unroll 1
  for (int pass = 0; pass < 2; ++pass){
    __syncthreads();
    {
      const char* wp = (const char*)(Wt + (size_t)pass * 64 * 256);
      #pragma unroll
      for (int j = 0; j < 8; ++j){
        int c = t + 256 * j;
        *(uint4*)(Bs + SWZ(c * 16)) = *(const uint4*)(wp + c * 16);
      }
    }
    __syncthreads();

    f32x4 acc[2][2];
    #pragma unroll
    for (int i = 0; i < 2; ++i)
      #pragma unroll
      for (int j = 0; j < 2; ++j)
        acc[i][j] = (f32x4){0.f, 0.f, 0.f, 0.f};

    #pragma unroll
    for (int kk = 0; kk < 8; ++kk){
      bf16x8 a[2], bfr[2];
      #pragma unroll
      for (int i = 0; i < 2; ++i){
        int ar = wm * 32 + i * 16 + l15;
        a[i]   = *(const bf16x8*)(As + SWZ(ar * 512 + kk * 64 + l4 * 16));
        int br = wn * 32 + i * 16 + l15;
        bfr[i] = *(const bf16x8*)(Bs + SWZ(br * 512 + kk * 64 + l4 * 16));
      }
      #pragma unroll
      for (int i = 0; i < 2; ++i)
        #pragma unroll
        for (int j = 0; j < 2; ++j)
          acc[i][j] = __builtin_amdgcn_mfma_f32_16x16x32_bf16(a[i], bfr[j], acc[i][j], 0, 0, 0);
    }
    __syncthreads();

    #pragma unroll
    for (int i = 0; i < 2; ++i)
      #pragma unroll
      for (int j = 0; j < 2; ++j)
        #pragma unroll
        for (int reg = 0; reg < 4; ++reg){
          int row = wm * 32 + i * 16 + l4 * 4 + reg;
          int colb = (wn * 32 + j * 16 + l15) * 2;
          *(unsigned short*)(Cs + row * 128 + (colb ^ ((row & 7) << 4))) = f2bf(acc[i][j][reg]);
        }
    __syncthreads();

    unsigned short* dst = pass ? vb : kb;
    #pragma unroll
    for (int q2 = 0; q2 < 2; ++q2){
      int idx = t + 256 * q2, r = idx >> 3, c = idx & 7;
      uint4 val = *(const uint4*)(Cs + r * 128 + ((c * 16) ^ ((r & 7) << 4)));
      *(uint4*)((char*)dst + ((size_t)(gm0 + r)) * 128 + c * 16) = val;
    }
  }
}

// ---------------------------------------------------------------------------
// transpose vb [B*N][64] -> vT [B][64][4096] (bf16), 64x64 tiles
__global__ __launch_bounds__(256) void k_vt(const unsigned short* __restrict__ vb,
                                            unsigned short* __restrict__ vT){
  __shared__ unsigned short T[64][72];
  const int t = threadIdx.x, b = blockIdx.y, n0 = blockIdx.x * 64;
  #pragma unroll
  for (int q = 0; q < 2; ++q){
    int idx = t + 256 * q, n = idx >> 3, c = idx & 7;
    uint4 val = *(const uint4*)(vb + ((size_t)(b * 4096 + n0 + n)) * 64 + c * 8);
    const unsigned short* e = (const unsigned short*)&val;
    #pragma unroll
    for (int j = 0; j < 8; ++j){
      int row = c * 8 + j;
      T[row][n ^ (((row >> 3) & 7) << 3)] = e[j];
    }
  }
  __syncthreads();
  #pragma unroll
  for (int q = 0; q < 2; ++q){
    int idx = t + 256 * q, dd = idx >> 3, c = idx & 7;
    int cc = c ^ ((dd >> 3) & 7);
    uint4 val = *(const uint4*)(&T[dd][cc * 8]);
    *(uint4*)(vT + ((size_t)(b * 64 + dd)) * 4096 + n0 + c * 8) = val;
  }
}

// ---------------------------------------------------------------------------
// initial q = LN(slots) @ Wq, one wave per (b,k)  (used once, before iter 0)
__global__ __launch_bounds__(64) void k_slotq(
    const float* __restrict__ slots, const float* __restrict__ lng, const float* __restrict__ lnb,
    const float* __restrict__ Wq, float* __restrict__ qws){
  int bk = blockIdx.x, d = threadIdx.x;
  float s = slots[bk * 64 + d];
  float s1 = s, s2 = s * s;
  #pragma unroll
  for (int off = 32; off >= 1; off >>= 1){
    s1 += __shfl_xor(s1, off);
    s2 += __shfl_xor(s2, off);
  }
  float m = s1 * (1.f / 64.f);
  float var = s2 * (1.f / 64.f) - m * m;
  float rstd = rsqrtf(var + 1e-5f);
  float xn = (s - m) * rstd * lng[d] + lnb[d];
  __shared__ __align__(16) float xsh[64];
  xsh[d] = xn;
  __syncthreads();
  float q = 0.f;
  #pragma unroll
  for (int i = 0; i < 64; ++i) q += xsh[i] * Wq[i * 64 + d];
  qws[bk * 64 + d] = q;
}

// ---------------------------------------------------------------------------
// MFMA attention (unchanged from R2)
__global__ __launch_bounds__(256) void k_attn2(
    const unsigned short* __restrict__ kb, const unsigned short* __restrict__ vT,
    const float* __restrict__ qws, float* __restrict__ Sws, float* __restrict__ Uws,
    float* __restrict__ attn_out, int write_attn){
  __shared__ __align__(16) char sm[45056];
  char* kT  = sm;            // [128][64] bf16 swz (16KB)
  char* vTs = sm + 16384;    // [64][128] bf16 swz (16KB)
  char* qs  = sm + 32768;    // [32][64] bf16 swz (4KB)
  char* Ps  = sm + 36864;    // [32][128] bf16 swz (8KB)
  const int t = threadIdx.x, lane = t & 63, w = t >> 6;
  const int l15 = lane & 15, g = lane >> 4;
  const int b = blockIdx.y, n0 = blockIdx.x * 128;

  if (t < 160){
    int r = t >> 3, c = t & 7;
    const float4* qp = (const float4*)(qws + (size_t)b * 1280 + r * 64 + c * 8);
    float4 a0 = qp[0], a1 = qp[1];
    uint4 pk;
    pk.x = (unsigned)f2bf(a0.x) | ((unsigned)f2bf(a0.y) << 16);
    pk.y = (unsigned)f2bf(a0.z) | ((unsigned)f2bf(a0.w) << 16);
    pk.z = (unsigned)f2bf(a1.x) | ((unsigned)f2bf(a1.y) << 16);
    pk.w = (unsigned)f2bf(a1.z) | ((unsigned)f2bf(a1.w) << 16);
    *(uint4*)(qs + r * 128 + ((c * 16) ^ ((r & 7) << 4))) = pk;
  }
  {
    const char* kbp = (const char*)kb + (size_t)b * 4096 * 128;
    #pragma unroll
    for (int j = 0; j < 4; ++j){
      int idx = t + 256 * j, r = idx >> 3, c = idx & 7;
      uint4 val = *(const uint4*)(kbp + ((size_t)(n0 + r)) * 128 + c * 16);
      *(uint4*)(kT + r * 128 + ((c * 16) ^ ((r & 7) << 4))) = val;
    }
  }
  {
    const char* vtp = (const char*)vT + (size_t)b * 64 * 8192;
    #pragma unroll
    for (int j = 0; j < 4; ++j){
      int idx = t + 256 * j, r = idx >> 4, c = idx & 15;
      uint4 val = *(const uint4*)(vtp + (size_t)r * 8192 + n0 * 2 + c * 16);
      *(uint4*)(vTs + r * 256 + ((c * 16) ^ ((r & 7) << 4))) = val;
    }
  }
  __syncthreads();

  f32x4 c2[2][2];
  #pragma unroll
  for (int kt = 0; kt < 2; ++kt)
    #pragma unroll
    for (int nt = 0; nt < 2; ++nt)
      c2[kt][nt] = (f32x4){0.f, 0.f, 0.f, 0.f};
  #pragma unroll
  for (int kst = 0; kst < 2; ++kst){
    bf16x8 aq[2], bk2[2];
    #pragma unroll
    for (int kt = 0; kt < 2; ++kt){
      int row = kt * 16 + l15;
      aq[kt] = *(const bf16x8*)(qs + row * 128 + ((kst * 64 + g * 16) ^ ((row & 7) << 4)));
    }
    #pragma unroll
    for (int nt = 0; nt < 2; ++nt){
      int row = w * 32 + nt * 16 + l15;
      bk2[nt] = *(const bf16x8*)(kT + row * 128 + ((kst * 64 + g * 16) ^ ((row & 7) << 4)));
    }
    #pragma unroll
    for (int kt = 0; kt < 2; ++kt)
      #pragma unroll
      for (int nt = 0; nt < 2; ++nt)
        c2[kt][nt] = __builtin_amdgcn_mfma_f32_16x16x32_bf16(aq[kt], bk2[nt], c2[kt][nt], 0, 0, 0);
  }

  float p[2][2][4];
  #pragma unroll
  for (int kt = 0; kt < 2; ++kt)
    #pragma unroll
    for (int nt = 0; nt < 2; ++nt)
      #pragma unroll
      for (int reg = 0; reg < 4; ++reg)
        p[kt][nt][reg] = c2[kt][nt][reg] * 0.125f;
  if (g){
    #pragma unroll
    for (int nt = 0; nt < 2; ++nt)
      #pragma unroll
      for (int reg = 0; reg < 4; ++reg)
        p[1][nt][reg] = -1e30f;
  }

  #pragma unroll
  for (int nt = 0; nt < 2; ++nt){
    float mx = p[0][nt][0];
    #pragma unroll
    for (int reg = 1; reg < 4; ++reg) mx = fmaxf(mx, p[0][nt][reg]);
    #pragma unroll
    for (int reg = 0; reg < 4; ++reg) mx = fmaxf(mx, p[1][nt][reg]);
    mx = fmaxf(mx, __shfl_xor(mx, 16));
    mx = fmaxf(mx, __shfl_xor(mx, 32));
    float s = 0.f;
    #pragma unroll
    for (int kt = 0; kt < 2; ++kt)
      #pragma unroll
      for (int reg = 0; reg < 4; ++reg){
        float e = __expf(p[kt][nt][reg] - mx);
        p[kt][nt][reg] = e; s += e;
      }
    s += __shfl_xor(s, 16);
    s += __shfl_xor(s, 32);
    float inv = 1.f / s;
    #pragma unroll
    for (int kt = 0; kt < 2; ++kt)
      #pragma unroll
      for (int reg = 0; reg < 4; ++reg)
        p[kt][nt][reg] *= inv;
  }

  {
    float sr[2][4];
    #pragma unroll
    for (int kt = 0; kt < 2; ++kt)
      #pragma unroll
      for (int reg = 0; reg < 4; ++reg)
        sr[kt][reg] = p[kt][0][reg] + p[kt][1][reg];
    #pragma unroll
    for (int off = 1; off <= 8; off <<= 1)
      #pragma unroll
      for (int kt = 0; kt < 2; ++kt)
        #pragma unroll
        for (int reg = 0; reg < 4; ++reg)
          sr[kt][reg] += __shfl_xor(sr[kt][reg], off);
    if (l15 == 0){
      #pragma unroll
      for (int kt = 0; kt < 2; ++kt)
        #pragma unroll
        for (int reg = 0; reg < 4; ++reg){
          int ks = kt * 16 + g * 4 + reg;
          if (ks < 20) atomicAdd(Sws + b * 20 + ks, sr[kt][reg]);
        }
    }
  }

  if (write_attn){
    #pragma unroll
    for (int kt = 0; kt < 2; ++kt)
      #pragma unroll
      for (int nt = 0; nt < 2; ++nt)
        #pragma unroll
        for (int reg = 0; reg < 4; ++reg){
          int ks = kt * 16 + g * 4 + reg;
          if (ks < 20)
            attn_out[((size_t)(b * 20 + ks)) * 4096 + n0 + w * 32 + nt * 16 + l15] = p[kt][nt][reg];
        }
  }

  #pragma unroll
  for (int kt = 0; kt < 2; ++kt)
    #pragma unroll
    for (int nt = 0; nt < 2; ++nt)
      #pragma unroll
      for (int reg = 0; reg < 4; ++reg){
        int row = kt * 16 + g * 4 + reg;
        int colb = (w * 32 + nt * 16 + l15) * 2;
        *(unsigned short*)(Ps + row * 256 + (colb ^ ((row & 7) << 4))) = f2bf(p[kt][nt][reg]);
      }
  __syncthreads();

  f32x4 u[2];
  u[0] = (f32x4){0.f,0.f,0.f,0.f};
  u[1] = (f32x4){0.f,0.f,0.f,0.f};
  #pragma unroll
  for (int kst = 0; kst < 4; ++kst){
    bf16x8 pa[2], bv;
    #pragma unroll
    for (int kt = 0; kt < 2; ++kt){
      int row = kt * 16 + l15;
      pa[kt] = *(const bf16x8*)(Ps + row * 256 + ((kst * 64 + g * 16) ^ ((row & 7) << 4)));
    }
    {
      int row = w * 16 + l15;
      bv = *(const bf16x8*)(vTs + row * 256 + ((kst * 64 + g * 16) ^ ((row & 7) << 4)));
    }
    #pragma unroll
    for (int kt = 0; kt < 2; ++kt)
      u[kt] = __builtin_amdgcn_mfma_f32_16x16x32_bf16(pa[kt], bv, u[kt], 0, 0, 0);
  }
  #pragma unroll
  for (int kt = 0; kt < 2; ++kt)
    #pragma unroll
    for (int reg = 0; reg < 4; ++reg){
      int ks = kt * 16 + g * 4 + reg;
      if (ks < 20)
        atomicAdd(Uws + ((size_t)(b * 20 + ks)) * 64 + w * 16 + l15, u[kt][reg]);
    }
}

// ---------------------------------------------------------------------------
// Fused slot update: updates=U/(S+eps) -> GRU -> LN -> MLP -> slots -> LN -> q(next)
// One block per batch b, 256 threads. All GEMMs via MFMA with pre-packed weights.
// Swapped operands: C[out_dim][slot] so per-slot elementwise ops are lane-local-ish.
__global__ __launch_bounds__(256) void k_slot(
    float* __restrict__ slots, const float* __restrict__ Uws, const float* __restrict__ Sws,
    const unsigned short* __restrict__ PWih, const unsigned short* __restrict__ PWhh,
    const unsigned short* __restrict__ PW1T, const unsigned short* __restrict__ PW2T,
    const unsigned short* __restrict__ PWq,
    const float* __restrict__ bih, const float* __restrict__ bhh,
    const float* __restrict__ b1, const float* __restrict__ b2,
    const float* __restrict__ lmg, const float* __restrict__ lmb,
    const float* __restrict__ lsg, const float* __restrict__ lsb,
    float* __restrict__ qws, float* __restrict__ out_slots, int last){
  extern __shared__ char sm[];
  float* g1f = (float*)sm;                 // [192][33] f32 (25,344B)
  float* g2f = g1f + 192 * 33;             // [192][33] f32
  char*  reluT = sm;                       // [32][256] bf16 swz512 (16KB) -- aliases g1f/g2f
  char*  ubf   = sm + 50688;               // [32][64] bf16 swz128 (4KB)
  char*  sbfb  = sm + 54784;               // [32][64] bf16 swz128 (4KB)
  char*  hbf   = sm + 58880;               // [32][64] bf16 swz128 (4KB)
  char*  sqbf  = sm + 62976;               // [32][64] bf16 swz128 (4KB)
  float* snewF = (float*)(sm + 67072);     // [32][65] f32 (8,320B)
  float* prevF = (float*)(sm + 75392);     // [32][65] f32
  float* sfinF = (float*)(sm + 83712);     // [32][65] f32  (total 92,032B)

  const int t = threadIdx.x, lane = t & 63, w = t >> 6;
  const int l15 = lane & 15, g4 = lane >> 4;
  const int b = blockIdx.x;

  // ---- phase 0: stage updates (U*rs) and prev slots as bf16 tiles + prev f32
  #pragma unroll
  for (int i = 0; i < 5; ++i){
    int idx = t + 256 * i;                 // 0..1279
    int m = idx >> 6, d = idx & 63;
    float rs = 1.f / (Sws[b * 20 + m] + 1e-8f);
    float uv = Uws[((size_t)b * 20 + m) * 64 + d] * rs;
    float pv = slots[((size_t)b * 20 + m) * 64 + d];
    int off = m * 128 + d * 2;
    *(unsigned short*)(ubf  + SWZ128(off)) = f2bf(uv);
    *(unsigned short*)(sbfb + SWZ128(off)) = f2bf(pv);
    prevF[m * 65 + d] = pv;
  }
  __syncthreads();

  // ---- phase 1: gates GEMMs. wave 0,1: G1 = U@Wih^T (mg = w); wave 2,3: G2 = S@Whh^T.
  {
    const unsigned short* PA = (w < 2) ? PWih : PWhh;
    const char* Bt = (w < 2) ? ubf : sbfb;
    float* gout = (w < 2) ? g1f : g2f;
    const int mg = w & 1;
    f32x4 acc[12];
    #pragma unroll
    for (int jt = 0; jt < 12; ++jt) acc[jt] = (f32x4){0.f,0.f,0.f,0.f};
    #pragma unroll
    for (int kst = 0; kst < 2; ++kst){
      int roff = (mg * 16 + l15) * 128 + (kst * 32 + g4 * 8) * 2;
      bf16x8 bfrag = *(const bf16x8*)(Bt + SWZ128(roff));
      #pragma unroll
      for (int jt = 0; jt < 12; ++jt){
        bf16x8 afrag = *(const bf16x8*)(PA + ((size_t)((jt * 2 + kst) * 64 + lane)) * 8);
        acc[jt] = __builtin_amdgcn_mfma_f32_16x16x32_bf16(afrag, bfrag, acc[jt], 0, 0, 0);
      }
    }
    #pragma unroll
    for (int jt = 0; jt < 12; ++jt)
      #pragma unroll
      for (int reg = 0; reg < 4; ++reg)
        gout[(jt * 16 + g4 * 4 + reg) * 33 + mg * 16 + l15] = acc[jt][reg];
  }
  __syncthreads();

  // ---- phase 2: gate combine + GRU + LayerNorm(mlp) -> h tile
  {
    const int d = lane;
    const float bi_r = bih[d], bi_z = bih[64 + d], bi_n = bih[128 + d];
    const float bh_r = bhh[d], bh_z = bhh[64 + d], bh_n = bhh[128 + d];
    const float lg = lmg[d], lb = lmb[d];
    #pragma unroll
    for (int mi = 0; mi < 5; ++mi){
      int m = w + mi * 4;                  // 0..19
      float i_r = g1f[d * 33 + m] + bi_r;
      float i_z = g1f[(64 + d) * 33 + m] + bi_z;
      float i_n = g1f[(128 + d) * 33 + m] + bi_n;
      float h_r = g2f[d * 33 + m] + bh_r;
      float h_z = g2f[(64 + d) * 33 + m] + bh_z;
      float h_n = g2f[(128 + d) * 33 + m] + bh_n;
      float r = 1.f / (1.f + __expf(-(i_r + h_r)));
      float z = 1.f / (1.f + __expf(-(i_z + h_z)));
      float nn = tanhf(i_n + r * h_n);
      float pv = prevF[m * 65 + d];
      float sn = (1.f - z) * nn + z * pv;
      snewF[m * 65 + d] = sn;
      float s1 = sn, s2 = sn * sn;
      #pragma unroll
      for (int off = 32; off >= 1; off >>= 1){
        s1 += __shfl_xor(s1, off);
        s2 += __shfl_xor(s2, off);
      }
      float mean = s1 * (1.f / 64.f);
      float var = s2 * (1.f / 64.f) - mean * mean;
      float rstd = rsqrtf(var + 1e-5f);
      float h = (sn - mean) * rstd * lg + lb;
      *(unsigned short*)(hbf + SWZ128(m * 128 + d * 2)) = f2bf(h);
    }
  }
  __syncthreads();

  // ---- phase 3: hid = relu(h@W1 + b1) -> reluT (aliases g bufs, safe post-barrier)
  {
    f32x4 acc[4][2];
    #pragma unroll
    for (int j4 = 0; j4 < 4; ++j4)
      #pragma unroll
      for (int mg = 0; mg < 2; ++mg)
        acc[j4][mg] = (f32x4){0.f,0.f,0.f,0.f};
    #pragma unroll
    for (int kst = 0; kst < 2; ++kst){
      bf16x8 bh2[2];
      #pragma unroll
      for (int mg = 0; mg < 2; ++mg){
        int roff = (mg * 16 + l15) * 128 + (kst * 32 + g4 * 8) * 2;
        bh2[mg] = *(const bf16x8*)(hbf + SWZ128(roff));
      }
      #pragma unroll
      for (int j4 = 0; j4 < 4; ++j4){
        int jt = w * 4 + j4;
        bf16x8 afrag = *(const bf16x8*)(PW1T + ((size_t)((jt * 2 + kst) * 64 + lane)) * 8);
        #pragma unroll
        for (int mg = 0; mg < 2; ++mg)
          acc[j4][mg] = __builtin_amdgcn_mfma_f32_16x16x32_bf16(afrag, bh2[mg], acc[j4][mg], 0, 0, 0);
      }
    }
    #pragma unroll
    for (int j4 = 0; j4 < 4; ++j4)
      #pragma unroll
      for (int reg = 0; reg < 4; ++reg){
        int j = (w * 4 + j4) * 16 + g4 * 4 + reg;
        float bb = b1[j];
        #pragma unroll
        for (int mg = 0; mg < 2; ++mg){
          float vv = fmaxf(acc[j4][mg][reg] + bb, 0.f);
          int m = mg * 16 + l15;
          int off = m * 512 + j * 2;
          *(unsigned short*)(reluT + SWZ(off)) = f2bf(vv);
        }
      }
  }
  __syncthreads();

  // ---- phase 4: out = relu@W2 + b2; slots_new = snew + out
  {
    f32x4 acc[2];
    acc[0] = (f32x4){0.f,0.f,0.f,0.f};
    acc[1] = (f32x4){0.f,0.f,0.f,0.f};
    #pragma unroll
    for (int kst = 0; kst < 8; ++kst){
      bf16x8 afrag = *(const bf16x8*)(PW2T + ((size_t)((w * 8 + kst) * 64 + lane)) * 8);
      #pragma unroll
      for (int mg = 0; mg < 2; ++mg){
        int row = mg * 16 + l15;
        int off = row * 512 + (kst * 32 + g4 * 8) * 2;
        bf16x8 bfrag = *(const bf16x8*)(reluT + SWZ(off));
        acc[mg] = __builtin_amdgcn_mfma_f32_16x16x32_bf16(afrag, bfrag, acc[mg], 0, 0, 0);
      }
    }
    #pragma unroll
    for (int mg = 0; mg < 2; ++mg)
      #pragma unroll
      for (int reg = 0; reg < 4; ++reg){
        int m = mg * 16 + l15;
        int dd = w * 16 + g4 * 4 + reg;
        if (m < 20){
          float sf = snewF[m * 65 + dd] + acc[mg][reg] + b2[dd];
          sfinF[m * 65 + dd] = sf;
          slots[((size_t)b * 20 + m) * 64 + dd] = sf;
          if (last) out_slots[((size_t)b * 20 + m) * 64 + dd] = sf;
        }
      }
  }
  if (last) return;
  __syncthreads();

  // ---- phase 5: q = LN_slot(slots_new) @ Wq for next iteration
  {
    const int d = lane;
    const float lg = lsg[d], lb = lsb[d];
    #pragma unroll
    for (int mi = 0; mi < 5; ++mi){
      int m = w + mi * 4;
      float sv = sfinF[m * 65 + d];
      float s1 = sv, s2 = sv * sv;
      #pragma unroll
      for (int off = 32; off >= 1; off >>= 1){
        s1 += __shfl_xor(s1, off);
        s2 += __shfl_xor(s2, off);
      }
      float mean = s1 * (1.f / 64.f);
      float var = s2 * (1.f / 64.f) - mean * mean;
      float rstd = rsqrtf(var + 1e-5f);
      float xn = (sv - mean) * rstd * lg + lb;
      *(unsigned short*)(sqbf + SWZ128(m * 128 + d * 2)) = f2bf(xn);
    }
  }
  __syncthreads();
  {
    f32x4 acc[2];
    acc[0] = (f32x4){0.f,0.f,0.f,0.f};
    acc[1] = (f32x4){0.f,0.f,0.f,0.f};
    #pragma unroll
    for (int kst = 0; kst < 2; ++kst){
      bf16x8 afrag = *(const bf16x8*)(PWq + ((size_t)((w * 2 + kst) * 64 + lane)) * 8);
      #pragma unroll
      for (int mg = 0; mg < 2; ++mg){
        int roff = (mg * 16 + l15) * 128 + (kst * 32 + g4 * 8) * 2;
        bf16x8 bfrag = *(const bf16x8*)(sqbf + SWZ128(roff));
        acc[mg] = __builtin_amdgcn_mfma_f32_16x16x32_bf16(afrag, bfrag, acc[mg], 0, 0, 0);
      }
    }
    #pragma unroll
    for (int mg = 0; mg < 2; ++mg)
      #pragma unroll
      for (int reg = 0; reg < 4; ++reg){
        int m = mg * 16 + l15;
        int j = w * 16 + g4 * 4 + reg;
        if (m < 20) qws[(size_t)b * 1280 + m * 64 + j] = acc[mg][reg];
      }
  }
}

// ---------------------------------------------------------------------------
extern "C" void kernel_launch(void* const* d_in, const int* in_sizes, int n_in,
                              void* d_out, int out_size, void* d_ws, size_t ws_size,
                              hipStream_t stream){
  const float* inputs = (const float*)d_in[0];
  const float* noise  = (const float*)d_in[1];
  const float* mu     = (const float*)d_in[2];
  const float* lsig   = (const float*)d_in[3];
  const float* ln_in_g= (const float*)d_in[4];
  const float* ln_in_b= (const float*)d_in[5];
  const float* Wk     = (const float*)d_in[6];
  const float* Wv     = (const float*)d_in[7];
  const float* Wq     = (const float*)d_in[8];
  const float* ln_s_g = (const float*)d_in[9];
  const float* ln_s_b = (const float*)d_in[10];
  const float* Wih    = (const float*)d_in[11];
  const float* Whh    = (const float*)d_in[12];
  const float* bih    = (const float*)d_in[13];
  const float* bhh    = (const float*)d_in[14];
  const float* lmg    = (const float*)d_in[15];
  const float* lmb    = (const float*)d_in[16];
  const float* W1     = (const float*)d_in[17];
  const float* b1     = (const float*)d_in[18];
  const float* W2     = (const float*)d_in[19];
  const float* b2     = (const float*)d_in[20];

  char* ws = (char*)d_ws;
  unsigned short* kb  = (unsigned short*)ws;                  // 33,554,432 B
  unsigned short* vb  = (unsigned short*)(ws + 33554432);     // 33,554,432 B
  unsigned short* vT  = (unsigned short*)(ws + 67108864);     // 33,554,432 B
  unsigned short* Wt  = (unsigned short*)(ws + 100663296);    // 65,536 B
  float* slots        = (float*)(ws + 100728832);             // 327,680 B
  float* qws          = (float*)(ws + 101056512);             // 327,680 B
  float* Uws          = (float*)(ws + 101384192);             // 327,680 B
  float* Sws          = (float*)(ws + 101711872);             // 5,120 B
  unsigned short* PWih= (unsigned short*)(ws + 101716992);    // 24,576 B
  unsigned short* PWhh= (unsigned short*)(ws + 101741568);    // 24,576 B
  unsigned short* PW1T= (unsigned short*)(ws + 101766144);    // 32,768 B
  unsigned short* PW2T= (unsigned short*)(ws + 101798912);    // 32,768 B
  unsigned short* PWq = (unsigned short*)(ws + 101831680);    // 8,192 B

  float* slots_out = (float*)d_out;
  float* attn_out  = slots_out + 81920;

  hipLaunchKernelGGL(k_wt,    dim3(128), dim3(256), 0, stream, Wk, Wv, Wt);
  hipLaunchKernelGGL(k_wprep, dim3(240), dim3(256), 0, stream, Wih, Whh, W1, W2, Wq,
                     PWih, PWhh, PW1T, PW2T, PWq);
  hipLaunchKernelGGL(k_init,  dim3(320), dim3(256), 0, stream, noise, mu, lsig, slots);
  hipLaunchKernelGGL(k_lnkv,  dim3(4096), dim3(256), 65536, stream, inputs, ln_in_g, ln_in_b, Wt, kb, vb);
  hipLaunchKernelGGL(k_vt,    dim3(64, 64), dim3(256), 0, stream, vb, vT);
  hipLaunchKernelGGL(k_slotq, dim3(1280), dim3(64), 0, stream, slots, ln_s_g, ln_s_b, Wq, qws);

  for (int it = 0; it < 3; ++it){
    hipMemsetAsync(Uws, 0, (81920 + 1280) * sizeof(float), stream);
    hipLaunchKernelGGL(k_attn2, dim3(32, 64), dim3(256), 0, stream, kb, vT, qws, Sws, Uws,
                       attn_out, (it == 2) ? 1 : 0);
    hipLaunchKernelGGL(k_slot, dim3(64), dim3(256), 92032, stream, slots, Uws, Sws,
                       PWih, PWhh, PW1T, PW2T, PWq, bih, bhh, b1, b2,
                       lmg, lmb, ln_s_g, ln_s_b, qws, slots_out, (it == 2) ? 1 : 0);
  }
}

// Round 4
// 333.473 us; speedup vs baseline: 2.2546x; 1.2562x over previous
//
#include <hip/hip_runtime.h>
#include <cstdint>
#include <cstddef>

using f32x4  = __attribute__((ext_vector_type(4))) float;
using bf16x8 = __attribute__((ext_vector_type(8))) short;

__device__ __forceinline__ float bflo(unsigned int u){ return __uint_as_float(u << 16); }
__device__ __forceinline__ unsigned short f2bf(float f){
  unsigned int u = __float_as_uint(f);
  return (unsigned short)((u + 0x7fffu + ((u >> 16) & 1u)) >> 16);
}

// swizzles: XOR 16B-slot bits with row&7 (row = 512B or 128B)
#define SWZ(o)    ((o) ^ ((((o) >> 9) & 7) << 4))
#define SWZ128(o) ((o) ^ ((((o) >> 7) & 7) << 4))

// ---------------------------------------------------------------------------
__global__ void k_wt(const float* __restrict__ Wk, const float* __restrict__ Wv,
                     unsigned short* __restrict__ Wt){
  int idx = blockIdx.x * 256 + threadIdx.x;   // 32768 total
  int n = idx >> 8, kk = idx & 255;
  float w = (n < 64) ? Wk[kk * 64 + n] : Wv[kk * 64 + (n - 64)];
  Wt[idx] = f2bf(w);
}

__global__ void k_init(const float* __restrict__ noise, const float* __restrict__ mu,
                       const float* __restrict__ lsig, float* __restrict__ slots){
  int idx = blockIdx.x * 256 + threadIdx.x;   // 81920 total
  int d = idx & 63;
  slots[idx] = mu[d] + __expf(lsig[d]) * noise[idx];
}

// ---------------------------------------------------------------------------
// Pack slot-path weights into MFMA A-fragment order (bf16).
__global__ void k_wprep(const float* __restrict__ Wih, const float* __restrict__ Whh,
                        const float* __restrict__ W1,  const float* __restrict__ W2,
                        const float* __restrict__ Wq,
                        unsigned short* __restrict__ PWih, unsigned short* __restrict__ PWhh,
                        unsigned short* __restrict__ PW1T, unsigned short* __restrict__ PW2T,
                        unsigned short* __restrict__ PWq){
  int idx = blockIdx.x * 256 + threadIdx.x;   // 61440 total
  int rel, kstN;
  const float* src; unsigned short* dst; int mode;
  if (idx < 12288)      { rel = idx;          kstN = 2; src = Wih; dst = PWih; mode = 0; }
  else if (idx < 24576) { rel = idx - 12288;  kstN = 2; src = Whh; dst = PWhh; mode = 0; }
  else if (idx < 40960) { rel = idx - 24576;  kstN = 2; src = W1;  dst = PW1T; mode = 1; }
  else if (idx < 57344) { rel = idx - 40960;  kstN = 8; src = W2;  dst = PW2T; mode = 2; }
  else                  { rel = idx - 57344;  kstN = 2; src = Wq;  dst = PWq;  mode = 3; }
  int e = rel & 7, lane = (rel >> 3) & 63, f = rel >> 9;
  int jt = f / kstN, kst = f - jt * kstN;
  int row = jt * 16 + (lane & 15);
  int col = kst * 32 + (lane >> 4) * 8 + e;
  float v;
  if (mode == 0)      v = src[row * 64 + col];
  else if (mode == 1) v = src[col * 256 + row];
  else if (mode == 2) v = src[col * 64 + row];
  else                v = src[col * 64 + row];
  dst[rel] = f2bf(v);
}

// ---------------------------------------------------------------------------
// Fused LN + (x@Wk | x@Wv) -> kb bf16 [B*N][64], vb bf16 [B*N][64]
__global__ __launch_bounds__(256) void k_lnkv(
    const float* __restrict__ x, const float* __restrict__ lng, const float* __restrict__ lnb,
    const unsigned short* __restrict__ Wt,
    unsigned short* __restrict__ kb, unsigned short* __restrict__ vb){
  extern __shared__ char smem[];
  char* As = smem;            // 64 x 256 bf16, swizzled (32KB)
  char* Bs = smem + 32768;    // 64 x 256 bf16, swizzled (32KB); Cs aliases this
  char* Cs = smem + 32768;    // 64 x 64 bf16 output staging (8KB, aliased)
  const int t = threadIdx.x;
  const int lane = t & 63, w = t >> 6;
  const int gm0 = blockIdx.x * 64;

  const float4 g4 = *(const float4*)(lng + lane * 4);
  const float4 b4 = *(const float4*)(lnb + lane * 4);

  #pragma unroll
  for (int bb = 0; bb < 2; ++bb){
    float4 xv[8];
    #pragma unroll
    for (int j = 0; j < 8; ++j){
      int r = w * 16 + bb * 8 + j;
      xv[j] = *(const float4*)(x + (size_t)(gm0 + r) * 256 + lane * 4);
    }
    #pragma unroll
    for (int j = 0; j < 8; ++j){
      int r = w * 16 + bb * 8 + j;
      float4 v = xv[j];
      float s  = v.x + v.y + v.z + v.w;
      float s2 = v.x * v.x + v.y * v.y + v.z * v.z + v.w * v.w;
      #pragma unroll
      for (int off = 32; off >= 1; off >>= 1){
        s  += __shfl_xor(s,  off);
        s2 += __shfl_xor(s2, off);
      }
      float mean = s * (1.f / 256.f);
      float var  = s2 * (1.f / 256.f) - mean * mean;
      float rstd = rsqrtf(var + 1e-5f);
      unsigned int p0 = (unsigned)f2bf((v.x - mean) * rstd * g4.x + b4.x) |
                        ((unsigned)f2bf((v.y - mean) * rstd * g4.y + b4.y) << 16);
      unsigned int p1 = (unsigned)f2bf((v.z - mean) * rstd * g4.z + b4.z) |
                        ((unsigned)f2bf((v.w - mean) * rstd * g4.w + b4.w) << 16);
      int off8 = r * 512 + lane * 8;
      *(uint2*)(As + SWZ(off8)) = make_uint2(p0, p1);
    }
  }

  const int wm = w >> 1, wn = w & 1;
  const int l15 = lane & 15, l4 = lane >> 4;

  #pragma unroll 1
  for (int pass = 0; pass < 2; ++pass){
    __syncthreads();
    {
      const char* wp = (const char*)(Wt + (size_t)pass * 64 * 256);
      #pragma unroll
      for (int j = 0; j < 8; ++j){
        int c = t + 256 * j;
        *(uint4*)(Bs + SWZ(c * 16)) = *(const uint4*)(wp + c * 16);
      }
    }
    __syncthreads();

    f32x4 acc[2][2];
    #pragma unroll
    for (int i = 0; i < 2; ++i)
      #pragma unroll
      for (int j = 0; j < 2; ++j)
        acc[i][j] = (f32x4){0.f, 0.f, 0.f, 0.f};

    #pragma unroll
    for (int kk = 0; kk < 8; ++kk){
      bf16x8 a[2], bfr[2];
      #pragma unroll
      for (int i = 0; i < 2; ++i){
        int ar = wm * 32 + i * 16 + l15;
        a[i]   = *(const bf16x8*)(As + SWZ(ar * 512 + kk * 64 + l4 * 16));
        int br = wn * 32 + i * 16 + l15;
        bfr[i] = *(const bf16x8*)(Bs + SWZ(br * 512 + kk * 64 + l4 * 16));
      }
      #pragma unroll
      for (int i = 0; i < 2; ++i)
        #pragma unroll
        for (int j = 0; j < 2; ++j)
          acc[i][j] = __builtin_amdgcn_mfma_f32_16x16x32_bf16(a[i], bfr[j], acc[i][j], 0, 0, 0);
    }
    __syncthreads();

    #pragma unroll
    for (int i = 0; i < 2; ++i)
      #pragma unroll
      for (int j = 0; j < 2; ++j)
        #pragma unroll
        for (int reg = 0; reg < 4; ++reg){
          int row = wm * 32 + i * 16 + l4 * 4 + reg;
          int colb = (wn * 32 + j * 16 + l15) * 2;
          *(unsigned short*)(Cs + row * 128 + (colb ^ ((row & 7) << 4))) = f2bf(acc[i][j][reg]);
        }
    __syncthreads();

    unsigned short* dst = pass ? vb : kb;
    #pragma unroll
    for (int q2 = 0; q2 < 2; ++q2){
      int idx = t + 256 * q2, r = idx >> 3, c = idx & 7;
      uint4 val = *(const uint4*)(Cs + r * 128 + ((c * 16) ^ ((r & 7) << 4)));
      *(uint4*)((char*)dst + ((size_t)(gm0 + r)) * 128 + c * 16) = val;
    }
  }
}

// ---------------------------------------------------------------------------
// transpose vb [B*N][64] -> vT [B][64][4096] (bf16), 64x64 tiles
__global__ __launch_bounds__(256) void k_vt(const unsigned short* __restrict__ vb,
                                            unsigned short* __restrict__ vT){
  __shared__ unsigned short T[64][72];
  const int t = threadIdx.x, b = blockIdx.y, n0 = blockIdx.x * 64;
  #pragma unroll
  for (int q = 0; q < 2; ++q){
    int idx = t + 256 * q, n = idx >> 3, c = idx & 7;
    uint4 val = *(const uint4*)(vb + ((size_t)(b * 4096 + n0 + n)) * 64 + c * 8);
    const unsigned short* e = (const unsigned short*)&val;
    #pragma unroll
    for (int j = 0; j < 8; ++j){
      int row = c * 8 + j;
      T[row][n ^ (((row >> 3) & 7) << 3)] = e[j];
    }
  }
  __syncthreads();
  #pragma unroll
  for (int q = 0; q < 2; ++q){
    int idx = t + 256 * q, dd = idx >> 3, c = idx & 7;
    int cc = c ^ ((dd >> 3) & 7);
    uint4 val = *(const uint4*)(&T[dd][cc * 8]);
    *(uint4*)(vT + ((size_t)(b * 64 + dd)) * 4096 + n0 + c * 8) = val;
  }
}

// ---------------------------------------------------------------------------
// initial q = LN(slots) @ Wq, one wave per (b,k)  (used once, before iter 0)
__global__ __launch_bounds__(64) void k_slotq(
    const float* __restrict__ slots, const float* __restrict__ lng, const float* __restrict__ lnb,
    const float* __restrict__ Wq, float* __restrict__ qws){
  int bk = blockIdx.x, d = threadIdx.x;
  float s = slots[bk * 64 + d];
  float s1 = s, s2 = s * s;
  #pragma unroll
  for (int off = 32; off >= 1; off >>= 1){
    s1 += __shfl_xor(s1, off);
    s2 += __shfl_xor(s2, off);
  }
  float m = s1 * (1.f / 64.f);
  float var = s2 * (1.f / 64.f) - m * m;
  float rstd = rsqrtf(var + 1e-5f);
  float xn = (s - m) * rstd * lng[d] + lnb[d];
  __shared__ __align__(16) float xsh[64];
  xsh[d] = xn;
  __syncthreads();
  float q = 0.f;
  #pragma unroll
  for (int i = 0; i < 64; ++i) q += xsh[i] * Wq[i * 64 + d];
  qws[bk * 64 + d] = q;
}

// ---------------------------------------------------------------------------
// MFMA attention. Per (b, 128-n chunk): QK^T -> softmax over ks -> P
// -> Spart[b][ks][chunk], attn write (last iter), Upart[b][chunk][ks][d] = P@v
// No atomics; no zero-init required (every read location written each iter).
__global__ __launch_bounds__(256) void k_attn2(
    const unsigned short* __restrict__ kb, const unsigned short* __restrict__ vT,
    const float* __restrict__ qws, float* __restrict__ Spart, float* __restrict__ Upart,
    float* __restrict__ attn_out, int write_attn){
  __shared__ __align__(16) char sm[45440];
  char* kT  = sm;            // [128][64] bf16 swz (16KB)
  char* vTs = sm + 16384;    // [64][128] bf16 swz (16KB)
  char* qs  = sm + 32768;    // [32][64] bf16 swz (4KB)
  char* Ps  = sm + 36864;    // [32][128] bf16 swz (8KB)
  float* sred = (float*)(sm + 45056);  // [20][4]
  const int t = threadIdx.x, lane = t & 63, w = t >> 6;
  const int l15 = lane & 15, g = lane >> 4;
  const int b = blockIdx.y, chunk = blockIdx.x, n0 = chunk * 128;

  if (t < 160){
    int r = t >> 3, c = t & 7;
    const float4* qp = (const float4*)(qws + (size_t)b * 1280 + r * 64 + c * 8);
    float4 a0 = qp[0], a1 = qp[1];
    uint4 pk;
    pk.x = (unsigned)f2bf(a0.x) | ((unsigned)f2bf(a0.y) << 16);
    pk.y = (unsigned)f2bf(a0.z) | ((unsigned)f2bf(a0.w) << 16);
    pk.z = (unsigned)f2bf(a1.x) | ((unsigned)f2bf(a1.y) << 16);
    pk.w = (unsigned)f2bf(a1.z) | ((unsigned)f2bf(a1.w) << 16);
    *(uint4*)(qs + r * 128 + ((c * 16) ^ ((r & 7) << 4))) = pk;
  }
  {
    const char* kbp = (const char*)kb + (size_t)b * 4096 * 128;
    #pragma unroll
    for (int j = 0; j < 4; ++j){
      int idx = t + 256 * j, r = idx >> 3, c = idx & 7;
      uint4 val = *(const uint4*)(kbp + ((size_t)(n0 + r)) * 128 + c * 16);
      *(uint4*)(kT + r * 128 + ((c * 16) ^ ((r & 7) << 4))) = val;
    }
  }
  {
    const char* vtp = (const char*)vT + (size_t)b * 64 * 8192;
    #pragma unroll
    for (int j = 0; j < 4; ++j){
      int idx = t + 256 * j, r = idx >> 4, c = idx & 15;
      uint4 val = *(const uint4*)(vtp + (size_t)r * 8192 + n0 * 2 + c * 16);
      *(uint4*)(vTs + r * 256 + ((c * 16) ^ ((r & 7) << 4))) = val;
    }
  }
  __syncthreads();

  f32x4 c2[2][2];
  #pragma unroll
  for (int kt = 0; kt < 2; ++kt)
    #pragma unroll
    for (int nt = 0; nt < 2; ++nt)
      c2[kt][nt] = (f32x4){0.f, 0.f, 0.f, 0.f};
  #pragma unroll
  for (int kst = 0; kst < 2; ++kst){
    bf16x8 aq[2], bk2[2];
    #pragma unroll
    for (int kt = 0; kt < 2; ++kt){
      int row = kt * 16 + l15;
      aq[kt] = *(const bf16x8*)(qs + row * 128 + ((kst * 64 + g * 16) ^ ((row & 7) << 4)));
    }
    #pragma unroll
    for (int nt = 0; nt < 2; ++nt){
      int row = w * 32 + nt * 16 + l15;
      bk2[nt] = *(const bf16x8*)(kT + row * 128 + ((kst * 64 + g * 16) ^ ((row & 7) << 4)));
    }
    #pragma unroll
    for (int kt = 0; kt < 2; ++kt)
      #pragma unroll
      for (int nt = 0; nt < 2; ++nt)
        c2[kt][nt] = __builtin_amdgcn_mfma_f32_16x16x32_bf16(aq[kt], bk2[nt], c2[kt][nt], 0, 0, 0);
  }

  float p[2][2][4];
  #pragma unroll
  for (int kt = 0; kt < 2; ++kt)
    #pragma unroll
    for (int nt = 0; nt < 2; ++nt)
      #pragma unroll
      for (int reg = 0; reg < 4; ++reg)
        p[kt][nt][reg] = c2[kt][nt][reg] * 0.125f;
  if (g){
    #pragma unroll
    for (int nt = 0; nt < 2; ++nt)
      #pragma unroll
      for (int reg = 0; reg < 4; ++reg)
        p[1][nt][reg] = -1e30f;
  }

  #pragma unroll
  for (int nt = 0; nt < 2; ++nt){
    float mx = p[0][nt][0];
    #pragma unroll
    for (int reg = 1; reg < 4; ++reg) mx = fmaxf(mx, p[0][nt][reg]);
    #pragma unroll
    for (int reg = 0; reg < 4; ++reg) mx = fmaxf(mx, p[1][nt][reg]);
    mx = fmaxf(mx, __shfl_xor(mx, 16));
    mx = fmaxf(mx, __shfl_xor(mx, 32));
    float s = 0.f;
    #pragma unroll
    for (int kt = 0; kt < 2; ++kt)
      #pragma unroll
      for (int reg = 0; reg < 4; ++reg){
        float e = __expf(p[kt][nt][reg] - mx);
        p[kt][nt][reg] = e; s += e;
      }
    s += __shfl_xor(s, 16);
    s += __shfl_xor(s, 32);
    float inv = 1.f / s;
    #pragma unroll
    for (int kt = 0; kt < 2; ++kt)
      #pragma unroll
      for (int reg = 0; reg < 4; ++reg)
        p[kt][nt][reg] *= inv;
  }

  // per-wave S sums -> sred[ks][w]
  {
    float sr[2][4];
    #pragma unroll
    for (int kt = 0; kt < 2; ++kt)
      #pragma unroll
      for (int reg = 0; reg < 4; ++reg)
        sr[kt][reg] = p[kt][0][reg] + p[kt][1][reg];
    #pragma unroll
    for (int off = 1; off <= 8; off <<= 1)
      #pragma unroll
      for (int kt = 0; kt < 2; ++kt)
        #pragma unroll
        for (int reg = 0; reg < 4; ++reg)
          sr[kt][reg] += __shfl_xor(sr[kt][reg], off);
    if (l15 == 0){
      #pragma unroll
      for (int kt = 0; kt < 2; ++kt)
        #pragma unroll
        for (int reg = 0; reg < 4; ++reg){
          int ks = kt * 16 + g * 4 + reg;
          if (ks < 20) sred[ks * 4 + w] = sr[kt][reg];
        }
    }
  }

  if (write_attn){
    #pragma unroll
    for (int kt = 0; kt < 2; ++kt)
      #pragma unroll
      for (int nt = 0; nt < 2; ++nt)
        #pragma unroll
        for (int reg = 0; reg < 4; ++reg){
          int ks = kt * 16 + g * 4 + reg;
          if (ks < 20)
            attn_out[((size_t)(b * 20 + ks)) * 4096 + n0 + w * 32 + nt * 16 + l15] = p[kt][nt][reg];
        }
  }

  #pragma unroll
  for (int kt = 0; kt < 2; ++kt)
    #pragma unroll
    for (int nt = 0; nt < 2; ++nt)
      #pragma unroll
      for (int reg = 0; reg < 4; ++reg){
        int row = kt * 16 + g * 4 + reg;
        int colb = (w * 32 + nt * 16 + l15) * 2;
        *(unsigned short*)(Ps + row * 256 + (colb ^ ((row & 7) << 4))) = f2bf(p[kt][nt][reg]);
      }
  __syncthreads();

  // block S sum -> Spart[b][ks][chunk]
  if (t < 20)
    Spart[((size_t)b * 20 + t) * 32 + chunk] =
        sred[t * 4 + 0] + sred[t * 4 + 1] + sred[t * 4 + 2] + sred[t * 4 + 3];

  f32x4 u[2];
  u[0] = (f32x4){0.f,0.f,0.f,0.f};
  u[1] = (f32x4){0.f,0.f,0.f,0.f};
  #pragma unroll
  for (int kst = 0; kst < 4; ++kst){
    bf16x8 pa[2], bv;
    #pragma unroll
    for (int kt = 0; kt < 2; ++kt){
      int row = kt * 16 + l15;
      pa[kt] = *(const bf16x8*)(Ps + row * 256 + ((kst * 64 + g * 16) ^ ((row & 7) << 4)));
    }
    {
      int row = w * 16 + l15;
      bv = *(const bf16x8*)(vTs + row * 256 + ((kst * 64 + g * 16) ^ ((row & 7) << 4)));
    }
    #pragma unroll
    for (int kt = 0; kt < 2; ++kt)
      u[kt] = __builtin_amdgcn_mfma_f32_16x16x32_bf16(pa[kt], bv, u[kt], 0, 0, 0);
  }
  #pragma unroll
  for (int kt = 0; kt < 2; ++kt)
    #pragma unroll
    for (int reg = 0; reg < 4; ++reg){
      int ks = kt * 16 + g * 4 + reg;
      if (ks < 20)
        Upart[((size_t)(b * 32 + chunk) * 20 + ks) * 64 + w * 16 + l15] = u[kt][reg];
    }
}

// ---------------------------------------------------------------------------
// Fused slot update: reduce partials -> updates -> GRU -> LN -> MLP -> slots -> LN -> q
// One block per batch b, 256 threads.
__global__ __launch_bounds__(256) void k_slot(
    float* __restrict__ slots, const float* __restrict__ Upart, const float* __restrict__ Spart,
    const unsigned short* __restrict__ PWih, const unsigned short* __restrict__ PWhh,
    const unsigned short* __restrict__ PW1T, const unsigned short* __restrict__ PW2T,
    const unsigned short* __restrict__ PWq,
    const float* __restrict__ bih, const float* __restrict__ bhh,
    const float* __restrict__ b1, const float* __restrict__ b2,
    const float* __restrict__ lmg, const float* __restrict__ lmb,
    const float* __restrict__ lsg, const float* __restrict__ lsb,
    float* __restrict__ qws, float* __restrict__ out_slots, int last){
  extern __shared__ char sm[];
  float* g1f = (float*)sm;                 // [192][33] f32 (25,344B)
  float* g2f = g1f + 192 * 33;             // [192][33] f32
  char*  reluT = sm;                       // [32][256] bf16 swz512 (16KB) -- aliases g1f/g2f
  char*  ubf   = sm + 50688;               // [32][64] bf16 swz128 (4KB)
  char*  sbfb  = sm + 54784;               // [32][64] bf16 swz128 (4KB)
  char*  hbf   = sm + 58880;               // [32][64] bf16 swz128 (4KB)
  char*  sqbf  = sm + 62976;               // [32][64] bf16 swz128 (4KB)
  float* snewF = (float*)(sm + 67072);     // [32][65] f32 (8,320B)
  float* prevF = (float*)(sm + 75392);     // [32][65] f32
  float* sfinF = (float*)(sm + 83712);     // [32][65] f32
  float* sSr   = (float*)(sm + 92032);     // [20] f32  (total 92,160B)

  const int t = threadIdx.x, lane = t & 63, w = t >> 6;
  const int l15 = lane & 15, g4 = lane >> 4;
  const int b = blockIdx.x;

  // ---- phase 0a: S reduction -> 1/(S+eps)
  if (t < 20){
    const float* sp = Spart + ((size_t)b * 20 + t) * 32;
    float ss = 0.f;
    #pragma unroll
    for (int c = 0; c < 32; ++c) ss += sp[c];
    sSr[t] = 1.f / (ss + 1e-8f);
  }
  __syncthreads();

  // ---- phase 0b: U reduction, stage updates and prev slots as bf16 tiles + prev f32
  #pragma unroll
  for (int i = 0; i < 5; ++i){
    int idx = t + 256 * i;                 // 0..1279
    int m = idx >> 6, d = idx & 63;
    const float* up = Upart + (size_t)b * 40960 + m * 64 + d;
    float uv = 0.f;
    #pragma unroll
    for (int c = 0; c < 32; ++c) uv += up[(size_t)c * 1280];
    uv *= sSr[m];
    float pv = slots[((size_t)b * 20 + m) * 64 + d];
    int off = m * 128 + d * 2;
    *(unsigned short*)(ubf  + SWZ128(off)) = f2bf(uv);
    *(unsigned short*)(sbfb + SWZ128(off)) = f2bf(pv);
    prevF[m * 65 + d] = pv;
  }
  __syncthreads();

  // ---- phase 1: gates GEMMs. wave 0,1: G1 = U@Wih^T; wave 2,3: G2 = S@Whh^T.
  {
    const unsigned short* PA = (w < 2) ? PWih : PWhh;
    const char* Bt = (w < 2) ? ubf : sbfb;
    float* gout = (w < 2) ? g1f : g2f;
    const int mg = w & 1;
    f32x4 acc[12];
    #pragma unroll
    for (int jt = 0; jt < 12; ++jt) acc[jt] = (f32x4){0.f,0.f,0.f,0.f};
    #pragma unroll
    for (int kst = 0; kst < 2; ++kst){
      int roff = (mg * 16 + l15) * 128 + (kst * 32 + g4 * 8) * 2;
      bf16x8 bfrag = *(const bf16x8*)(Bt + SWZ128(roff));
      #pragma unroll
      for (int jt = 0; jt < 12; ++jt){
        bf16x8 afrag = *(const bf16x8*)(PA + ((size_t)((jt * 2 + kst) * 64 + lane)) * 8);
        acc[jt] = __builtin_amdgcn_mfma_f32_16x16x32_bf16(afrag, bfrag, acc[jt], 0, 0, 0);
      }
    }
    #pragma unroll
    for (int jt = 0; jt < 12; ++jt)
      #pragma unroll
      for (int reg = 0; reg < 4; ++reg)
        gout[(jt * 16 + g4 * 4 + reg) * 33 + mg * 16 + l15] = acc[jt][reg];
  }
  __syncthreads();

  // ---- phase 2: gate combine + GRU + LayerNorm(mlp) -> h tile
  {
    const int d = lane;
    const float bi_r = bih[d], bi_z = bih[64 + d], bi_n = bih[128 + d];
    const float bh_r = bhh[d], bh_z = bhh[64 + d], bh_n = bhh[128 + d];
    const float lg = lmg[d], lb = lmb[d];
    #pragma unroll
    for (int mi = 0; mi < 5; ++mi){
      int m = w + mi * 4;                  // 0..19
      float i_r = g1f[d * 33 + m] + bi_r;
      float i_z = g1f[(64 + d) * 33 + m] + bi_z;
      float i_n = g1f[(128 + d) * 33 + m] + bi_n;
      float h_r = g2f[d * 33 + m] + bh_r;
      float h_z = g2f[(64 + d) * 33 + m] + bh_z;
      float h_n = g2f[(128 + d) * 33 + m] + bh_n;
      float r = 1.f / (1.f + __expf(-(i_r + h_r)));
      float z = 1.f / (1.f + __expf(-(i_z + h_z)));
      float nn = tanhf(i_n + r * h_n);
      float pv = prevF[m * 65 + d];
      float sn = (1.f - z) * nn + z * pv;
      snewF[m * 65 + d] = sn;
      float s1 = sn, s2 = sn * sn;
      #pragma unroll
      for (int off = 32; off >= 1; off >>= 1){
        s1 += __shfl_xor(s1, off);
        s2 += __shfl_xor(s2, off);
      }
      float mean = s1 * (1.f / 64.f);
      float var = s2 * (1.f / 64.f) - mean * mean;
      float rstd = rsqrtf(var + 1e-5f);
      float h = (sn - mean) * rstd * lg + lb;
      *(unsigned short*)(hbf + SWZ128(m * 128 + d * 2)) = f2bf(h);
    }
  }
  __syncthreads();

  // ---- phase 3: hid = relu(h@W1 + b1) -> reluT (aliases g bufs, safe post-barrier)
  {
    f32x4 acc[4][2];
    #pragma unroll
    for (int j4 = 0; j4 < 4; ++j4)
      #pragma unroll
      for (int mg = 0; mg < 2; ++mg)
        acc[j4][mg] = (f32x4){0.f,0.f,0.f,0.f};
    #pragma unroll
    for (int kst = 0; kst < 2; ++kst){
      bf16x8 bh2[2];
      #pragma unroll
      for (int mg = 0; mg < 2; ++mg){
        int roff = (mg * 16 + l15) * 128 + (kst * 32 + g4 * 8) * 2;
        bh2[mg] = *(const bf16x8*)(hbf + SWZ128(roff));
      }
      #pragma unroll
      for (int j4 = 0; j4 < 4; ++j4){
        int jt = w * 4 + j4;
        bf16x8 afrag = *(const bf16x8*)(PW1T + ((size_t)((jt * 2 + kst) * 64 + lane)) * 8);
        #pragma unroll
        for (int mg = 0; mg < 2; ++mg)
          acc[j4][mg] = __builtin_amdgcn_mfma_f32_16x16x32_bf16(afrag, bh2[mg], acc[j4][mg], 0, 0, 0);
      }
    }
    #pragma unroll
    for (int j4 = 0; j4 < 4; ++j4)
      #pragma unroll
      for (int reg = 0; reg < 4; ++reg){
        int j = (w * 4 + j4) * 16 + g4 * 4 + reg;
        float bb = b1[j];
        #pragma unroll
        for (int mg = 0; mg < 2; ++mg){
          float vv = fmaxf(acc[j4][mg][reg] + bb, 0.f);
          int m = mg * 16 + l15;
          int off = m * 512 + j * 2;
          *(unsigned short*)(reluT + SWZ(off)) = f2bf(vv);
        }
      }
  }
  __syncthreads();

  // ---- phase 4: out = relu@W2 + b2; slots_new = snew + out
  {
    f32x4 acc[2];
    acc[0] = (f32x4){0.f,0.f,0.f,0.f};
    acc[1] = (f32x4){0.f,0.f,0.f,0.f};
    #pragma unroll
    for (int kst = 0; kst < 8; ++kst){
      bf16x8 afrag = *(const bf16x8*)(PW2T + ((size_t)((w * 8 + kst) * 64 + lane)) * 8);
      #pragma unroll
      for (int mg = 0; mg < 2; ++mg){
        int row = mg * 16 + l15;
        int off = row * 512 + (kst * 32 + g4 * 8) * 2;
        bf16x8 bfrag = *(const bf16x8*)(reluT + SWZ(off));
        acc[mg] = __builtin_amdgcn_mfma_f32_16x16x32_bf16(afrag, bfrag, acc[mg], 0, 0, 0);
      }
    }
    #pragma unroll
    for (int mg = 0; mg < 2; ++mg)
      #pragma unroll
      for (int reg = 0; reg < 4; ++reg){
        int m = mg * 16 + l15;
        int dd = w * 16 + g4 * 4 + reg;
        if (m < 20){
          float sf = snewF[m * 65 + dd] + acc[mg][reg] + b2[dd];
          sfinF[m * 65 + dd] = sf;
          slots[((size_t)b * 20 + m) * 64 + dd] = sf;
          if (last) out_slots[((size_t)b * 20 + m) * 64 + dd] = sf;
        }
      }
  }
  if (last) return;
  __syncthreads();

  // ---- phase 5: q = LN_slot(slots_new) @ Wq for next iteration
  {
    const int d = lane;
    const float lg = lsg[d], lb = lsb[d];
    #pragma unroll
    for (int mi = 0; mi < 5; ++mi){
      int m = w + mi * 4;
      float sv = sfinF[m * 65 + d];
      float s1 = sv, s2 = sv * sv;
      #pragma unroll
      for (int off = 32; off >= 1; off >>= 1){
        s1 += __shfl_xor(s1, off);
        s2 += __shfl_xor(s2, off);
      }
      float mean = s1 * (1.f / 64.f);
      float var = s2 * (1.f / 64.f) - mean * mean;
      float rstd = rsqrtf(var + 1e-5f);
      float xn = (sv - mean) * rstd * lg + lb;
      *(unsigned short*)(sqbf + SWZ128(m * 128 + d * 2)) = f2bf(xn);
    }
  }
  __syncthreads();
  {
    f32x4 acc[2];
    acc[0] = (f32x4){0.f,0.f,0.f,0.f};
    acc[1] = (f32x4){0.f,0.f,0.f,0.f};
    #pragma unroll
    for (int kst = 0; kst < 2; ++kst){
      bf16x8 afrag = *(const bf16x8*)(PWq + ((size_t)((w * 2 + kst) * 64 + lane)) * 8);
      #pragma unroll
      for (int mg = 0; mg < 2; ++mg){
        int roff = (mg * 16 + l15) * 128 + (kst * 32 + g4 * 8) * 2;
        bf16x8 bfrag = *(const bf16x8*)(sqbf + SWZ128(roff));
        acc[mg] = __builtin_amdgcn_mfma_f32_16x16x32_bf16(afrag, bfrag, acc[mg], 0, 0, 0);
      }
    }
    #pragma unroll
    for (int mg = 0; mg < 2; ++mg)
      #pragma unroll
      for (int reg = 0; reg < 4; ++reg){
        int m = mg * 16 + l15;
        int j = w * 16 + g4 * 4 + reg;
        if (m < 20) qws[(size_t)b * 1280 + m * 64 + j] = acc[mg][reg];
      }
  }
}

// ---------------------------------------------------------------------------
extern "C" void kernel_launch(void* const* d_in, const int* in_sizes, int n_in,
                              void* d_out, int out_size, void* d_ws, size_t ws_size,
                              hipStream_t stream){
  const float* inputs = (const float*)d_in[0];
  const float* noise  = (const float*)d_in[1];
  const float* mu     = (const float*)d_in[2];
  const float* lsig   = (const float*)d_in[3];
  const float* ln_in_g= (const float*)d_in[4];
  const float* ln_in_b= (const float*)d_in[5];
  const float* Wk     = (const float*)d_in[6];
  const float* Wv     = (const float*)d_in[7];
  const float* Wq     = (const float*)d_in[8];
  const float* ln_s_g = (const float*)d_in[9];
  const float* ln_s_b = (const float*)d_in[10];
  const float* Wih    = (const float*)d_in[11];
  const float* Whh    = (const float*)d_in[12];
  const float* bih    = (const float*)d_in[13];
  const float* bhh    = (const float*)d_in[14];
  const float* lmg    = (const float*)d_in[15];
  const float* lmb    = (const float*)d_in[16];
  const float* W1     = (const float*)d_in[17];
  const float* b1     = (const float*)d_in[18];
  const float* W2     = (const float*)d_in[19];
  const float* b2     = (const float*)d_in[20];

  char* ws = (char*)d_ws;
  unsigned short* kb  = (unsigned short*)ws;                   // 33,554,432 B
  unsigned short* vb  = (unsigned short*)(ws + 33554432);      // 33,554,432 B
  unsigned short* vT  = (unsigned short*)(ws + 67108864);      // 33,554,432 B
  unsigned short* Wt  = (unsigned short*)(ws + 100663296);     // 65,536 B
  float* slots        = (float*)(ws + 100728832);              // 327,680 B
  float* qws          = (float*)(ws + 101056512);              // 327,680 B
  float* Upart        = (float*)(ws + 101384192);              // 10,485,760 B
  float* Spart        = (float*)(ws + 111869952);              // 163,840 B
  unsigned short* PWih= (unsigned short*)(ws + 112033792);     // 24,576 B
  unsigned short* PWhh= (unsigned short*)(ws + 112058368);     // 24,576 B
  unsigned short* PW1T= (unsigned short*)(ws + 112082944);     // 32,768 B
  unsigned short* PW2T= (unsigned short*)(ws + 112115712);     // 32,768 B
  unsigned short* PWq = (unsigned short*)(ws + 112148480);     // 8,192 B

  float* slots_out = (float*)d_out;
  float* attn_out  = slots_out + 81920;

  hipLaunchKernelGGL(k_wt,    dim3(128), dim3(256), 0, stream, Wk, Wv, Wt);
  hipLaunchKernelGGL(k_wprep, dim3(240), dim3(256), 0, stream, Wih, Whh, W1, W2, Wq,
                     PWih, PWhh, PW1T, PW2T, PWq);
  hipLaunchKernelGGL(k_init,  dim3(320), dim3(256), 0, stream, noise, mu, lsig, slots);
  hipLaunchKernelGGL(k_lnkv,  dim3(4096), dim3(256), 65536, stream, inputs, ln_in_g, ln_in_b, Wt, kb, vb);
  hipLaunchKernelGGL(k_vt,    dim3(64, 64), dim3(256), 0, stream, vb, vT);
  hipLaunchKernelGGL(k_slotq, dim3(1280), dim3(64), 0, stream, slots, ln_s_g, ln_s_b, Wq, qws);

  for (int it = 0; it < 3; ++it){
    hipLaunchKernelGGL(k_attn2, dim3(32, 64), dim3(256), 0, stream, kb, vT, qws, Spart, Upart,
                       attn_out, (it == 2) ? 1 : 0);
    hipLaunchKernelGGL(k_slot, dim3(64), dim3(256), 92160, stream, slots, Upart, Spart,
                       PWih, PWhh, PW1T, PW2T, PWq, bih, bhh, b1, b2,
                       lmg, lmb, ln_s_g, ln_s_b, qws, slots_out, (it == 2) ? 1 : 0);
  }
}